// Round 3
// baseline (337.140 us; speedup 1.0000x reference)
//
#include <hip/hip_runtime.h>
#include <hip/hip_bf16.h>

#define FEAT 256

typedef __attribute__((ext_vector_type(8))) short short8;
typedef __attribute__((ext_vector_type(4))) float floatx4;

__device__ __forceinline__ short f2bf(float f) {
    __hip_bfloat16 h = __float2bfloat16(f);   // RTNE; pairs fuse to v_cvt_pk_bf16_f32
    return __builtin_bit_cast(short, h);
}

// Block = 1024 threads = 16 waves = 4 row-groups x 4 col-quarters.
// Block tile = 64 rows x 256 cols: the block reads each x row ONCE (per
// row-group wave; the 4 col-quarter waves sharing those rows hit L1) and
// produces ALL 256 output columns -> no cross-CU x re-fetch (R2's bug).
// Full gamma staged as bf16 in 128 KiB LDS, FRAGMENT-ORDERED:
//   chunk(ntg,ks,grp,l15) = ((ntg*8+ks)*4 + grp)*16 + l15   (16 B chunks)
// so B-fragment reads are ds_read_b128 at wave-uniform base + lane*16,
// conflict-free, compile-time offsets. 1 block/CU (LDS-limited), 16 waves/CU.
__global__ __launch_bounds__(1024, 4) void gdn_kernel(
    const float* __restrict__ x,
    const float* __restrict__ beta,
    const float* __restrict__ gamma,
    float* __restrict__ out,
    int batch)
{
    __shared__ short8 ldsB[8192];   // 128 KiB = full 256x256 gamma in bf16

    const int tid  = threadIdx.x;
    const int lane = tid & 63;
    const int wave = tid >> 6;      // 0..15
    const int rg   = wave >> 2;     // row group 0..3
    const int cq   = wave & 3;      // col quarter 0..3
    const int l15  = lane & 15;
    const int grp  = lane >> 4;

    // ---- stage gamma -> LDS (bf16, fragment order). 8192 chunks / 1024 thr = 8 each.
    #pragma unroll
    for (int t = 0; t < 8; ++t) {
        const int ch   = tid + t * 1024;
        const int c_l  = ch & 15;
        const int c_g  = (ch >> 4) & 3;
        const int c_ks = (ch >> 6) & 7;
        const int c_nt = ch >> 9;               // 0..15
        const int col  = c_nt * 16 + c_l;
        const int k0   = c_ks * 32 + c_g * 8;   // same k-hat map as A (self-consistent)
        short8 b;
        #pragma unroll
        for (int i = 0; i < 8; ++i)
            b[i] = f2bf(gamma[(size_t)(k0 + i) * FEAT + col]);
        ldsB[ch] = b;
    }

    float bc[4];
    #pragma unroll
    for (int nt = 0; nt < 4; ++nt)
        bc[nt] = fmaxf(beta[cq * 64 + nt * 16 + l15], 1e-6f);

    __syncthreads();   // LDS read-only afterwards; no barriers in the loop

    const short8* Blane = ldsB + grp * 16 + l15;

    const int nrt = batch >> 6;                 // 64-row tiles (4096)
    for (int rt = blockIdx.x; rt < nrt; rt += gridDim.x) {
        const int rb = (rt << 6) + rg * 16;     // this wave's 16 rows

        // ---- A fragments: x^2 as bf16. Lane reads row (rb+l15),
        // k = ks*32 + grp*8 + i. Per (ks) the 4 grp-chunks cover one full
        // 128 B line of the row -> line-granular coalescing, L1 mops v1.
        short8 Af[8];
        const float* xrow = x + (size_t)(rb + l15) * FEAT + grp * 8;
        #pragma unroll
        for (int ks = 0; ks < 8; ++ks) {
            const floatx4* p = (const floatx4*)(xrow + ks * 32);
            floatx4 v0 = p[0];
            floatx4 v1 = p[1];
            short8 a;
            #pragma unroll
            for (int i = 0; i < 4; ++i) {
                a[i]     = f2bf(v0[i] * v0[i]);
                a[4 + i] = f2bf(v1[i] * v1[i]);
            }
            Af[ks] = a;
        }

        // ---- MFMA over K=256; B streamed from LDS (linear, conflict-free)
        floatx4 acc[4] = {{0.f,0.f,0.f,0.f},{0.f,0.f,0.f,0.f},
                          {0.f,0.f,0.f,0.f},{0.f,0.f,0.f,0.f}};
        #pragma unroll
        for (int ks = 0; ks < 8; ++ks) {
            #pragma unroll
            for (int nt = 0; nt < 4; ++nt) {
                const int ntg = cq * 4 + nt;    // global n-tile 0..15
                acc[nt] = __builtin_amdgcn_mfma_f32_16x16x32_bf16(
                    Af[ks], Blane[(ntg * 8 + ks) * 64], acc[nt], 0, 0, 0);
            }
        }

        // ---- Epilogue: y = x * rsqrt(acc + beta_c)
        // C/D layout: col = lane&15, row = (lane>>4)*4 + reg.
        // x re-read is same-wave rows loaded ~2K cyc ago -> L1/L2 hot.
        #pragma unroll
        for (int nt = 0; nt < 4; ++nt) {
            const int col = cq * 64 + nt * 16 + l15;
            #pragma unroll
            for (int r = 0; r < 4; ++r) {
                const int row = rb + grp * 4 + r;
                const size_t idx = (size_t)row * FEAT + col;
                out[idx] = x[idx] * rsqrtf(acc[nt][r] + bc[nt]);
            }
        }
    }
}

extern "C" void kernel_launch(void* const* d_in, const int* in_sizes, int n_in,
                              void* d_out, int out_size, void* d_ws, size_t ws_size,
                              hipStream_t stream) {
    const float* x     = (const float*)d_in[0];
    const float* beta  = (const float*)d_in[1];
    const float* gamma = (const float*)d_in[2];
    float* out = (float*)d_out;

    const int batch = in_sizes[0] / FEAT;   // 262144

    dim3 grid(256);     // persistent: 1 block/CU (128 KiB LDS), 16 iters each
    dim3 block(1024);   // 16 waves = 4 row-groups x 4 col-quarters
    hipLaunchKernelGGL(gdn_kernel, grid, block, 0, stream,
                       x, beta, gamma, out, batch);
}

// Round 4
// 270.131 us; speedup vs baseline: 1.2481x; 1.2481x over previous
//
#include <hip/hip_runtime.h>
#include <hip/hip_bf16.h>

#define FEAT 256

typedef __attribute__((ext_vector_type(8))) short short8;
typedef __attribute__((ext_vector_type(4))) float floatx4;

__device__ __forceinline__ short f2bf(float f) {
    __hip_bfloat16 h = __float2bfloat16(f);   // RTNE; pairs fuse to v_cvt_pk_bf16_f32
    return __builtin_bit_cast(short, h);
}

// R1 structure (B in registers, no LDS, no barriers) with halved per-wave
// column slice to double occupancy:
//   wave w owns cols [32w, 32w+32)  -> B-frags = 2 nt x 8 ks = 64 VGPRs
//   block = 512 thr = 8 waves = 16 rows x 256 cols (col-split WITHIN block,
//   so each x row is HBM-fetched once and the epilogue re-read is L1/L2-hot)
//   __launch_bounds__(512,4) -> ~128 VGPR cap -> 4 waves/SIMD (2x R1).
// out is write-once -> nontemporal stores keep x resident in L2/L3.
__global__ __launch_bounds__(512, 4) void gdn_kernel(
    const float* __restrict__ x,
    const float* __restrict__ beta,
    const float* __restrict__ gamma,
    float* __restrict__ out,
    int batch)
{
    const int lane = threadIdx.x & 63;
    const int wave = threadIdx.x >> 6;     // 0..7 -> 32-col slice
    const int l15  = lane & 15;
    const int grp  = lane >> 4;
    const int colbase = wave * 32;

    // ---- One-time: B fragments (gamma as bf16) into 64 VGPRs.
    // B[nt][ks] elem i = gamma[k][col], k = ks*32 + grp*8 + i (same k-hat
    // map as A below -> contraction correct under any HW intra-frag order).
    short8 Bf[2][8];
    #pragma unroll
    for (int nt = 0; nt < 2; ++nt) {
        const int col = colbase + nt * 16 + l15;
        #pragma unroll
        for (int ks = 0; ks < 8; ++ks) {
            const int k0 = ks * 32 + grp * 8;
            short8 b;
            #pragma unroll
            for (int i = 0; i < 8; ++i)
                b[i] = f2bf(gamma[(size_t)(k0 + i) * FEAT + col]);
            Bf[nt][ks] = b;
        }
    }

    float bc[2];
    #pragma unroll
    for (int nt = 0; nt < 2; ++nt)
        bc[nt] = fmaxf(beta[colbase + nt * 16 + l15], 1e-6f);

    const int ntiles = batch >> 4;          // 16-row tiles (16384)
    for (int t = blockIdx.x; t < ntiles; t += gridDim.x) {
        const int rb = t << 4;

        // ---- A fragments: x^2 as bf16. Lane reads row (rb+l15),
        // k = ks*32 + grp*8 + i; per ks the wave covers 16 rows x 128 B
        // contiguous segments -> full-line coalescing.
        short8 Af[8];
        const float* xrow = x + (size_t)(rb + l15) * FEAT + grp * 8;
        #pragma unroll
        for (int ks = 0; ks < 8; ++ks) {
            const floatx4* p = (const floatx4*)(xrow + ks * 32);
            floatx4 v0 = p[0];
            floatx4 v1 = p[1];
            short8 a;
            #pragma unroll
            for (int i = 0; i < 4; ++i) {
                a[i]     = f2bf(v0[i] * v0[i]);
                a[4 + i] = f2bf(v1[i] * v1[i]);
            }
            Af[ks] = a;
        }

        // ---- MFMA over K=256 (16 MFMA, all operands in regs)
        floatx4 acc[2] = {{0.f,0.f,0.f,0.f},{0.f,0.f,0.f,0.f}};
        #pragma unroll
        for (int ks = 0; ks < 8; ++ks) {
            #pragma unroll
            for (int nt = 0; nt < 2; ++nt) {
                acc[nt] = __builtin_amdgcn_mfma_f32_16x16x32_bf16(
                    Af[ks], Bf[nt][ks], acc[nt], 0, 0, 0);
            }
        }

        // ---- Epilogue: y = x * rsqrt(acc + beta_c)
        // C/D layout: col = lane&15, row = (lane>>4)*4 + reg.
        // x re-read: same rows this wave just loaded -> L1/L2 hot.
        #pragma unroll
        for (int nt = 0; nt < 2; ++nt) {
            const int col = colbase + nt * 16 + l15;
            #pragma unroll
            for (int r = 0; r < 4; ++r) {
                const int row = rb + grp * 4 + r;
                const size_t idx = (size_t)row * FEAT + col;
                float y = x[idx] * rsqrtf(acc[nt][r] + bc[nt]);
                __builtin_nontemporal_store(y, &out[idx]);
            }
        }
    }
}

extern "C" void kernel_launch(void* const* d_in, const int* in_sizes, int n_in,
                              void* d_out, int out_size, void* d_ws, size_t ws_size,
                              hipStream_t stream) {
    const float* x     = (const float*)d_in[0];
    const float* beta  = (const float*)d_in[1];
    const float* gamma = (const float*)d_in[2];
    float* out = (float*)d_out;

    const int batch = in_sizes[0] / FEAT;   // 262144

    dim3 grid(512);     // 2 blocks/CU x 8 waves = 16 waves/CU resident; 32 iters
    dim3 block(512);    // 8 waves: col-split within block
    hipLaunchKernelGGL(gdn_kernel, grid, block, 0, stream,
                       x, beta, gamma, out, batch);
}

// Round 5
// 115.674 us; speedup vs baseline: 2.9146x; 2.3353x over previous
//
#include <hip/hip_runtime.h>
#include <hip/hip_bf16.h>

#define FEAT   256
#define TROWS  16
#define TBYTES (TROWS * FEAT * 4)   // 16 KiB per x-tile

typedef __attribute__((ext_vector_type(8))) short  short8;
typedef __attribute__((ext_vector_type(4))) float  floatx4;

__device__ __forceinline__ short f2bf(float f) {
    __hip_bfloat16 h = __float2bfloat16(f);   // RTNE; pairs fuse to v_cvt_pk_bf16_f32
    return __builtin_bit_cast(short, h);
}

// Byte-offset swizzle within a 16-row x-tile: XOR bits 4..6 with row&7
// (row = offset>>10, 1024 B per row). Involution; preserves 16 B alignment.
// Applied to BOTH the global-load-lds SOURCE and every LDS READ (linear dest),
// so LDS holds a permuted tile and column-slice reads are bank-conflict-free.
__device__ __forceinline__ unsigned swz(unsigned o) {
    return o ^ (((o >> 10) & 7u) << 4);
}

// R1 skeleton (4 waves, wave w owns cols [64w,64w+64), B-frags in regs/AGPRs,
// col-split WITHIN block so x is fetched once) + T3 minimum 2-phase pipeline:
//   prologue: STAGE(buf0, t0); barrier
//   loop:     STAGE(buf^1, t+stride)   // async global->LDS, in flight...
//             compute tile t from buf  // ...under this compute
//             __syncthreads(); flip
// Epilogue x comes from LDS (no global re-read). 2 blocks/CU (32 KiB LDS each).
__global__ __launch_bounds__(256, 2) void gdn_kernel(
    const float* __restrict__ x,
    const float* __restrict__ beta,
    const float* __restrict__ gamma,
    float* __restrict__ out,
    int batch)
{
    __shared__ char ldsx[2 * TBYTES];   // double-buffered x tile, 32 KiB

    const int tid  = threadIdx.x;
    const int lane = tid & 63;
    const int wave = tid >> 6;          // 0..3 -> 64-col slice
    const int l15  = lane & 15;
    const int grp  = lane >> 4;
    const int colbase = wave * 64;

    // ---- One-time: B fragments (gamma as bf16), 128 regs (compiler -> AGPR).
    // k-hat map k = ks*32 + grp*8 + i, identical for A and B (self-consistent).
    short8 Bf[4][8];
    #pragma unroll
    for (int nt = 0; nt < 4; ++nt) {
        const int col = colbase + nt * 16 + l15;
        #pragma unroll
        for (int ks = 0; ks < 8; ++ks) {
            const int k0 = ks * 32 + grp * 8;
            short8 b;
            #pragma unroll
            for (int i = 0; i < 8; ++i)
                b[i] = f2bf(gamma[(size_t)(k0 + i) * FEAT + col]);
            Bf[nt][ks] = b;
        }
    }

    float bc[4];
    #pragma unroll
    for (int nt = 0; nt < 4; ++nt)
        bc[nt] = fmaxf(beta[colbase + nt * 16 + l15], 1e-6f);

    const int ntiles = batch >> 4;      // 16384
    const int stride = gridDim.x;       // 512 -> exactly 32 iters/block

    // Async stage of tile t into LDS buffer `buf`:
    // dest is LINEAR (wave-uniform base + lane*16, as HW requires);
    // source offset is pre-swizzled (same involution as the reads).
    auto STAGE = [&](int buf, int t) {
        const char* gb = (const char*)x + (size_t)t * TBYTES;
        #pragma unroll
        for (int r = 0; r < 4; ++r) {
            const unsigned d = (unsigned)(tid * 16 + r * 4096);
            __builtin_amdgcn_global_load_lds(
                (const __attribute__((address_space(1))) void*)(gb + swz(d)),
                (__attribute__((address_space(3))) void*)(&ldsx[buf * TBYTES] + d),
                16, 0, 0);
        }
    };

    int cur = 0;
    STAGE(0, blockIdx.x);
    __syncthreads();    // drain prologue stage (vmcnt0 + barrier)

    for (int t = blockIdx.x; t < ntiles; t += stride) {
        const int tn = t + stride;
        if (tn < ntiles) STAGE(cur ^ 1, tn);   // prefetch next tile under compute

        const char* lb = &ldsx[cur * TBYTES];

        // ---- A fragments from LDS: row l15, floats [ks*32+grp*8, +8).
        // Swizzled addr: banks spread over 8 slots per 16-lane group -> 2-way max.
        const unsigned p0 = (unsigned)(l15 * 1024 + grp * 32);
        const unsigned xv = (unsigned)((l15 & 7) << 4);
        short8 Af[8];
        #pragma unroll
        for (int ks = 0; ks < 8; ++ks) {
            floatx4 v0 = *(const floatx4*)(lb + (((p0 + ks * 128))      ^ xv));
            floatx4 v1 = *(const floatx4*)(lb + (((p0 + ks * 128 + 16)) ^ xv));
            short8 a;
            #pragma unroll
            for (int i = 0; i < 4; ++i) {
                a[i]     = f2bf(v0[i] * v0[i]);
                a[4 + i] = f2bf(v1[i] * v1[i]);
            }
            Af[ks] = a;
        }

        // ---- MFMA over K=256: 32 MFMA, 4 independent acc chains.
        floatx4 acc[4] = {{0.f,0.f,0.f,0.f},{0.f,0.f,0.f,0.f},
                          {0.f,0.f,0.f,0.f},{0.f,0.f,0.f,0.f}};
        #pragma unroll
        for (int ks = 0; ks < 8; ++ks) {
            #pragma unroll
            for (int nt = 0; nt < 4; ++nt) {
                acc[nt] = __builtin_amdgcn_mfma_f32_16x16x32_bf16(
                    Af[ks], Bf[nt][ks], acc[nt], 0, 0, 0);
            }
        }

        // ---- Epilogue: y = x * rsqrt(acc + beta_c); x re-read from LDS.
        // C/D layout: col = lane&15, row = (lane>>4)*4 + reg.
        const int rb = t << 4;
        #pragma unroll
        for (int nt = 0; nt < 4; ++nt) {
            const int col = colbase + nt * 16 + l15;
            #pragma unroll
            for (int r = 0; r < 4; ++r) {
                const int row = grp * 4 + r;                 // 0..15 within tile
                const unsigned eo = (unsigned)(row * 1024 + col * 4);
                const float xval = *(const float*)(lb + (eo ^ (((unsigned)(row & 7)) << 4)));
                out[(size_t)(rb + row) * FEAT + col] = xval * rsqrtf(acc[nt][r] + bc[nt]);
            }
        }

        __syncthreads();   // stage(t+1) drained + all waves done reading buf
        cur ^= 1;
    }
}

extern "C" void kernel_launch(void* const* d_in, const int* in_sizes, int n_in,
                              void* d_out, int out_size, void* d_ws, size_t ws_size,
                              hipStream_t stream) {
    const float* x     = (const float*)d_in[0];
    const float* beta  = (const float*)d_in[1];
    const float* gamma = (const float*)d_in[2];
    float* out = (float*)d_out;

    const int batch = in_sizes[0] / FEAT;   // 262144

    dim3 grid(512);     // 2 blocks/CU, 32 tiles each (exact, no tail)
    dim3 block(256);    // 4 waves: col-split within block
    hipLaunchKernelGGL(gdn_kernel, grid, block, 0, stream,
                       x, beta, gamma, out, batch);
}

// Round 6
// 108.387 us; speedup vs baseline: 3.1105x; 1.0672x over previous
//
#include <hip/hip_runtime.h>
#include <hip/hip_bf16.h>

#define FEAT   256
#define TROWS  16
#define TBYTES (TROWS * FEAT * 4)   // 16 KiB per x-tile
#define NBUF   3                    // depth-3 pipeline: loads lead compute by 2 tiles

typedef __attribute__((ext_vector_type(8))) short  short8;
typedef __attribute__((ext_vector_type(4))) float  floatx4;

__device__ __forceinline__ short f2bf(float f) {
    __hip_bfloat16 h = __float2bfloat16(f);   // RTNE; pairs fuse to v_cvt_pk_bf16_f32
    return __builtin_bit_cast(short, h);
}

// Byte-offset swizzle within a 16-row x-tile: XOR bits 4..6 with row&7
// (row = offset>>10). Involution, 16 B-granular. Applied to the gload_lds
// SOURCE (dest linear, as HW requires) and to every LDS READ.
__device__ __forceinline__ unsigned swz(unsigned o) {
    return o ^ (((o >> 10) & 7u) << 4);
}

// R5 skeleton + T4 counted-vmcnt pipeline (never drain vmcnt to 0 in loop):
//   iter t:  s_barrier                      // slot (t+2)%3 free (read at t-1)
//            STAGE(slot (t+2)%3, tile t+2)  // 4 gload_lds/wave, fire-and-forget
//            s_waitcnt vmcnt(8)             // own tile-t loads retired (in-order);
//                                           // t+1,t+2 (8 insts) stay in flight
//            s_barrier                      // => ALL waves' t-loads landed
//            compute tile t from slot t%3
// Tail: clamped redundant re-stage keeps vmcnt(8) uniform (slot-safe).
__global__ __launch_bounds__(256, 2) void gdn_kernel(
    const float* __restrict__ x,
    const float* __restrict__ beta,
    const float* __restrict__ gamma,
    float* __restrict__ out,
    int batch)
{
    __shared__ char ldsx[NBUF * TBYTES];   // 48 KiB -> still 2 blocks/CU

    const int tid  = threadIdx.x;
    const int lane = tid & 63;
    const int wave = tid >> 6;          // 0..3 -> 64-col slice
    const int l15  = lane & 15;
    const int grp  = lane >> 4;
    const int colbase = wave * 64;

    // ---- One-time: B fragments (gamma as bf16), 128 regs (unified VGPR/AGPR).
    // k-hat map k = ks*32 + grp*8 + i, identical for A and B (self-consistent).
    short8 Bf[4][8];
    #pragma unroll
    for (int nt = 0; nt < 4; ++nt) {
        const int col = colbase + nt * 16 + l15;
        #pragma unroll
        for (int ks = 0; ks < 8; ++ks) {
            const int k0 = ks * 32 + grp * 8;
            short8 b;
            #pragma unroll
            for (int i = 0; i < 8; ++i)
                b[i] = f2bf(gamma[(size_t)(k0 + i) * FEAT + col]);
            Bf[nt][ks] = b;
        }
    }

    float bc[4];
    #pragma unroll
    for (int nt = 0; nt < 4; ++nt)
        bc[nt] = fmaxf(beta[colbase + nt * 16 + l15], 1e-6f);

    const int ntiles = batch >> 4;      // 16384
    const int stride = gridDim.x;       // 512 -> exactly 32 iters/block
    const int iters  = ntiles / stride; // 32 (exact)
    const int t0     = blockIdx.x;

    // Async stage of tile `t` into LDS slot `s`: dest LINEAR (wave-uniform
    // base + lane*16), source pre-swizzled with the same involution as reads.
    auto STAGE = [&](int s, int t) {
        const char* gb = (const char*)x + (size_t)t * TBYTES;
        char* lbase = &ldsx[s * TBYTES];
        #pragma unroll
        for (int r = 0; r < 4; ++r) {
            const unsigned d = (unsigned)(tid * 16 + r * 4096);
            __builtin_amdgcn_global_load_lds(
                (const __attribute__((address_space(1))) void*)(gb + swz(d)),
                (__attribute__((address_space(3))) void*)(lbase + d),
                16, 0, 0);
        }
    };

    // Prologue: 2 tiles in flight before first compute.
    STAGE(0, t0);
    STAGE(1, t0 + stride);

    for (int it = 0; it < iters; ++it) {
        // Barrier A: every wave finished READING slot (it+2)%3 (at iter it-1).
        __builtin_amdgcn_s_barrier();
        __builtin_amdgcn_sched_barrier(0);

        int itn = it + 2;
        if (itn >= iters) itn = iters - 1;          // redundant re-stage in tail
        STAGE((it + 2) % NBUF, t0 + itn * stride);  // (slot-safe; never read)

        // Own tile-it loads retired (vmcnt in-order); 8 newer stay in flight.
        asm volatile("s_waitcnt vmcnt(8)" ::: "memory");
        __builtin_amdgcn_sched_barrier(0);
        // Barrier B: all waves passed vmcnt(8) -> tile-it fully in LDS.
        __builtin_amdgcn_s_barrier();
        __builtin_amdgcn_sched_barrier(0);

        const char* lb = &ldsx[(it % NBUF) * TBYTES];

        // ---- A fragments from LDS: row l15, floats [ks*32+grp*8, +8).
        const unsigned p0 = (unsigned)(l15 * 1024 + grp * 32);
        const unsigned xv = (unsigned)((l15 & 7) << 4);
        short8 Af[8];
        #pragma unroll
        for (int ks = 0; ks < 8; ++ks) {
            floatx4 v0 = *(const floatx4*)(lb + ((p0 + ks * 128)      ^ xv));
            floatx4 v1 = *(const floatx4*)(lb + ((p0 + ks * 128 + 16) ^ xv));
            short8 a;
            #pragma unroll
            for (int i = 0; i < 4; ++i) {
                a[i]     = f2bf(v0[i] * v0[i]);
                a[4 + i] = f2bf(v1[i] * v1[i]);
            }
            Af[ks] = a;
        }

        // ---- MFMA over K=256: 32 MFMA, 4 independent acc chains.
        floatx4 acc[4] = {{0.f,0.f,0.f,0.f},{0.f,0.f,0.f,0.f},
                          {0.f,0.f,0.f,0.f},{0.f,0.f,0.f,0.f}};
        #pragma unroll
        for (int ks = 0; ks < 8; ++ks) {
            #pragma unroll
            for (int nt = 0; nt < 4; ++nt) {
                acc[nt] = __builtin_amdgcn_mfma_f32_16x16x32_bf16(
                    Af[ks], Bf[nt][ks], acc[nt], 0, 0, 0);
            }
        }

        // ---- Epilogue: y = x * rsqrt(acc + beta_c); x re-read from LDS.
        // C/D layout: col = lane&15, row = (lane>>4)*4 + reg.
        const int rb = (t0 + it * stride) << 4;
        #pragma unroll
        for (int nt = 0; nt < 4; ++nt) {
            const int col = colbase + nt * 16 + l15;
            #pragma unroll
            for (int r = 0; r < 4; ++r) {
                const int row = grp * 4 + r;                 // 0..15 within tile
                const unsigned eo = (unsigned)(row * 1024 + col * 4);
                const float xval = *(const float*)(lb + (eo ^ (((unsigned)(row & 7)) << 4)));
                out[(size_t)(rb + row) * FEAT + col] = xval * rsqrtf(acc[nt][r] + bc[nt]);
            }
        }
        // no drain here: next iter's Barrier A only needs reg-held reads done.
    }
}

extern "C" void kernel_launch(void* const* d_in, const int* in_sizes, int n_in,
                              void* d_out, int out_size, void* d_ws, size_t ws_size,
                              hipStream_t stream) {
    const float* x     = (const float*)d_in[0];
    const float* beta  = (const float*)d_in[1];
    const float* gamma = (const float*)d_in[2];
    float* out = (float*)d_out;

    const int batch = in_sizes[0] / FEAT;   // 262144

    dim3 grid(512);     // 2 blocks/CU, exactly 32 tiles each
    dim3 block(256);    // 4 waves: col-split within block
    hipLaunchKernelGGL(gdn_kernel, grid, block, 0, stream,
                       x, beta, gamma, out, batch);
}